// Round 7
// baseline (606.279 us; speedup 1.0000x reference)
//
#include <hip/hip_runtime.h>
#include <math.h>

// Problem constants (from reference)
#define NHEAD 2
#define NDIM  64
#define HD    128   // NHEAD*NDIM
#define NGRAPH 64
#define NCLS  5
#define NEG_SLOPE 0.2f

typedef __attribute__((ext_vector_type(8))) short bf16x8;
typedef __attribute__((ext_vector_type(4))) float f32x4;

static __device__ __forceinline__ unsigned short f2bf(float f) {
    unsigned int u = __float_as_uint(f);
    u = (u + 0x7fff + ((u >> 16) & 1)) >> 16;   // round-to-nearest-even
    return (unsigned short)u;
}
static __device__ __forceinline__ float bf2f(unsigned short b) {
    return __uint_as_float((unsigned int)b << 16);
}

// ---------------- CSR build ----------------

__global__ void k_deg(const int* __restrict__ dst, int* __restrict__ deg, int E) {
    int i = blockIdx.x * blockDim.x + threadIdx.x;
    if (i < E) atomicAdd(&deg[dst[i]], 1);
}

__global__ __launch_bounds__(256) void k_scan_local(const int* __restrict__ deg,
                                                    int* __restrict__ ptr,
                                                    int* __restrict__ bsum, int n) {
    __shared__ int wsum[4];
    const int tid = threadIdx.x, lane = tid & 63, wid = tid >> 6;
    const int base = blockIdx.x * 2048 + tid * 8;
    int v[8];
    #pragma unroll
    for (int k = 0; k < 8; ++k) {
        int i = base + k;
        v[k] = (i < n) ? deg[i] : 0;
    }
    #pragma unroll
    for (int k = 1; k < 8; ++k) v[k] += v[k - 1];
    int x = v[7];
    #pragma unroll
    for (int off = 1; off < 64; off <<= 1) {
        int t = __shfl_up(x, off, 64);
        if (lane >= off) x += t;
    }
    if (lane == 63) wsum[wid] = x;
    __syncthreads();
    int woff = 0;
    #pragma unroll
    for (int k = 0; k < 4; ++k) woff += (k < wid) ? wsum[k] : 0;
    int texcl = woff + x - v[7];
    #pragma unroll
    for (int k = 0; k < 8; ++k) {
        int i = base + k;
        if (i < n) ptr[i + 1] = texcl + v[k];
    }
    if (tid == 255) bsum[blockIdx.x] = woff + x;
    if (blockIdx.x == 0 && tid == 0) ptr[0] = 0;
}

__global__ void k_scan_bsum(int* __restrict__ bsum, int B) {
    int lane = threadIdx.x;
    int carry = 0;
    for (int base = 0; base < B; base += 64) {
        int i = base + lane;
        int v = (i < B) ? bsum[i] : 0;
        int x = v;
        #pragma unroll
        for (int off = 1; off < 64; off <<= 1) {
            int t = __shfl_up(x, off, 64);
            if (lane >= off) x += t;
        }
        if (i < B) bsum[i] = carry + x - v;
        carry += __shfl(x, 63, 64);
    }
}

__global__ __launch_bounds__(256) void k_scan_add(int* __restrict__ ptr,
                                                  const int* __restrict__ bsum, int n) {
    int off = bsum[blockIdx.x];
    if (off == 0) return;
    const int base = blockIdx.x * 2048 + threadIdx.x * 8;
    #pragma unroll
    for (int k = 0; k < 8; ++k) {
        int i = base + k;
        if (i < n) ptr[i + 1] += off;
    }
}

// scatter also records the dst node of each CSR slot (needed by k_edge_exp)
__global__ void k_scatter(const int* __restrict__ src, const int* __restrict__ dst,
                          const int* __restrict__ ptr, int* __restrict__ fill,
                          int* __restrict__ csr, int* __restrict__ dstE, int E) {
    int i = blockIdx.x * blockDim.x + threadIdx.x;
    if (i < E) {
        int d = dst[i];
        int pos = atomicAdd(&fill[d], 1);
        int slot = ptr[d] + pos;
        csr[slot] = src[i];
        dstE[slot] = d;
    }
}

// ---------------- weight prep: fp32 W[k][n] -> bf16 Wt[n][k] for layers 2-4 ------

__global__ void k_prepw(const float* __restrict__ W2, const float* __restrict__ W3,
                        const float* __restrict__ W4, unsigned short* __restrict__ Wt) {
    int idx = blockIdx.x * blockDim.x + threadIdx.x;
    if (idx >= 3 * HD * HD) return;
    int l = idx / (HD * HD), rem = idx % (HD * HD);
    int n = rem >> 7, k = rem & 127;
    const float* W = (l == 0) ? W2 : (l == 1) ? W3 : W4;
    Wt[idx] = f2bf(W[k * HD + n]);
}

// ---------------- layer 1: x[N,4] @ W[4,128] + fused alpha dots ----------------
// Output h stored QUARTERED: plane q (dims [32q,32q+32)) at hq + q*NS, [N][32].
__global__ void k_gemm1_alpha(const float* __restrict__ x, const float* __restrict__ W,
                              const float* __restrict__ asrc, const float* __restrict__ adst,
                              unsigned short* __restrict__ hq, float* __restrict__ oas,
                              float* __restrict__ oad, int N) {
    const size_t NS = (size_t)N * 32;
    int n = (blockIdx.x * blockDim.x + threadIdx.x) >> 6;
    int lane = threadIdx.x & 63;
    if (n >= N) return;
    float4 xv = *(const float4*)&x[n * 4];
    int c0 = lane * 2;
    float2 w0 = *(const float2*)&W[c0];
    float2 w1 = *(const float2*)&W[128 + c0];
    float2 w2 = *(const float2*)&W[256 + c0];
    float2 w3 = *(const float2*)&W[384 + c0];
    float v0 = xv.x * w0.x + xv.y * w1.x + xv.z * w2.x + xv.w * w3.x;
    float v1 = xv.x * w0.y + xv.y * w1.y + xv.z * w2.y + xv.w * w3.y;
    unsigned short b0 = f2bf(v0), b1 = f2bf(v1);
    unsigned int packed = (unsigned int)b0 | ((unsigned int)b1 << 16);
    int p = lane >> 4;           // plane = (2*lane)>>5
    int off = c0 & 31;           // offset within plane row
    *(unsigned int*)&hq[(size_t)p * NS + (size_t)n * 32 + off] = packed;
    float vx = bf2f(b0), vy = bf2f(b1);
    float2 av = *(const float2*)&asrc[c0];
    float2 dv = *(const float2*)&adst[c0];
    float s = vx * av.x + vy * av.y;
    float t = vx * dv.x + vy * dv.y;
    #pragma unroll
    for (int off2 = 16; off2 > 0; off2 >>= 1) {
        s += __shfl_xor(s, off2);
        t += __shfl_xor(t, off2);
    }
    if ((lane & 31) == 0) {
        int head = lane >> 5;
        oas[n * 2 + head] = s;
        oad[n * 2 + head] = t;
    }
}

// ---------------- A1: per-edge exp(leaky(as[src]+ad[dst])), both heads -------
// oas/oad pools are 400 KB -> L2-resident gathers. No max-subtraction needed
// (|e| ~ O(5); clamp at 80 guards overflow; alpha = exp(e)/sum is identical).
__global__ void k_edge_exp(const int* __restrict__ csr, const int* __restrict__ dstE,
                           const float* __restrict__ oas, const float* __restrict__ oad,
                           float* __restrict__ expE, int E) {
    int i = blockIdx.x * blockDim.x + threadIdx.x;
    if (i >= E) return;
    int s = csr[i], d = dstE[i];
    float2 as = *(const float2*)&oas[s * 2];
    float2 ad = *(const float2*)&oad[d * 2];
    float e0 = as.x + ad.x; e0 = (e0 >= 0.f) ? e0 : NEG_SLOPE * e0;
    float e1 = as.y + ad.y; e1 = (e1 >= 0.f) ? e1 : NEG_SLOPE * e1;
    e0 = fminf(e0, 80.f); e1 = fminf(e1, 80.f);
    *(float2*)&expE[(size_t)i * 2] = make_float2(__expf(e0), __expf(e1));
}

// ---------------- A2: per-node 1/(sum exp + 1e-16), both heads ---------------
// 4-lane team per node; coalesced expE reads.
__global__ __launch_bounds__(256) void k_node_inv(const int* __restrict__ ptr,
                                                  const float* __restrict__ expE,
                                                  float* __restrict__ invL, int N) {
    int t = blockIdx.x * blockDim.x + threadIdx.x;
    int n = t >> 2, l4 = t & 3;
    if (n >= N) return;
    int beg = ptr[n], end = ptr[n + 1];
    float s0 = 0.f, s1 = 0.f;
    for (int j = beg + l4; j < end; j += 4) {
        float2 p = *(const float2*)&expE[(size_t)j * 2];
        s0 += p.x; s1 += p.y;
    }
    s0 += __shfl_xor(s0, 1); s0 += __shfl_xor(s0, 2);
    s1 += __shfl_xor(s1, 1); s1 += __shfl_xor(s1, 2);
    if (l4 == 0)
        *(float2*)&invL[n * 2] = make_float2(1.f / (s0 + 1e-16f), 1.f / (s1 + 1e-16f));
}

// ---------------- B: quarter-phased weighted gather-aggregate ----------------
// blockIdx.y = quarter q (slowest-varying -> temporal phasing: each phase
// gathers 64B/edge from ONE 3.2MB plane that fits the 4MB per-XCD L2).
// 4-lane team per node (64 nodes/block). Streams (csr, expE) use nontemporal
// loads so they don't evict the resident plane. Epilogue: +bias, relu.
__global__ __launch_bounds__(256) void k_gather_q(
    const unsigned short* __restrict__ hin,   // quartered planes
    const float* __restrict__ expE, const float* __restrict__ invL,
    const int* __restrict__ ptr, const int* __restrict__ csr,
    const float* __restrict__ bias,
    unsigned short* __restrict__ out_q,       // quartered output (mid layers)
    unsigned short* __restrict__ out_rm,      // row-major output (final layer)
    int rowmajor, int N) {
    const size_t NS = (size_t)N * 32;
    const int q = blockIdx.y;
    const int t = threadIdx.x >> 2, l4 = threadIdx.x & 3;
    const int n = blockIdx.x * 64 + t;
    if (n >= N) return;
    const int head = q >> 1;
    const int beg = ptr[n], end = ptr[n + 1];
    const float inv = invL[n * 2 + head];
    const unsigned short* __restrict__ hp = hin + (size_t)q * NS;
    float acc[8];
    #pragma unroll
    for (int k = 0; k < 8; ++k) acc[k] = 0.f;
    for (int j = beg; j < end; ++j) {
        int s = __builtin_nontemporal_load(&csr[j]);
        float pe = __builtin_nontemporal_load(&expE[(size_t)j * 2 + head]);
        float a = pe * inv;
        uint4 hv = *(const uint4*)&hp[(size_t)s * 32 + l4 * 8];
        #pragma unroll
        for (int k = 0; k < 4; ++k) {
            unsigned int u = (&hv.x)[k];
            acc[2 * k]     += a * __uint_as_float(u << 16);
            acc[2 * k + 1] += a * __uint_as_float(u & 0xffff0000u);
        }
    }
    const int dimb = q * 32 + l4 * 8;
    float4 ba = *(const float4*)&bias[dimb];
    float4 bb = *(const float4*)&bias[dimb + 4];
    float o[8];
    o[0] = fmaxf(acc[0] + ba.x, 0.f);
    o[1] = fmaxf(acc[1] + ba.y, 0.f);
    o[2] = fmaxf(acc[2] + ba.z, 0.f);
    o[3] = fmaxf(acc[3] + ba.w, 0.f);
    o[4] = fmaxf(acc[4] + bb.x, 0.f);
    o[5] = fmaxf(acc[5] + bb.y, 0.f);
    o[6] = fmaxf(acc[6] + bb.z, 0.f);
    o[7] = fmaxf(acc[7] + bb.w, 0.f);
    uint4 pk;
    pk.x = (unsigned int)f2bf(o[0]) | ((unsigned int)f2bf(o[1]) << 16);
    pk.y = (unsigned int)f2bf(o[2]) | ((unsigned int)f2bf(o[3]) << 16);
    pk.z = (unsigned int)f2bf(o[4]) | ((unsigned int)f2bf(o[5]) << 16);
    pk.w = (unsigned int)f2bf(o[6]) | ((unsigned int)f2bf(o[7]) << 16);
    if (rowmajor)
        *(uint4*)&out_rm[(size_t)n * HD + dimb] = pk;
    else
        *(uint4*)&out_q[(size_t)q * NS + (size_t)n * 32 + l4 * 8] = pk;
}

// ---------------- GEMM (layers 2-4): quartered A, MFMA 16x16x32 --------------
// LDS-free (round-4 verified structure). A fragment for K-slice ks lives
// entirely in plane ks. Output written quartered; fused alpha row-dots.
__global__ __launch_bounds__(256) void k_gemm_mfma(
    const unsigned short* __restrict__ Aq,
    const unsigned short* __restrict__ Wt,
    const float* __restrict__ asrc, const float* __restrict__ adst,
    unsigned short* __restrict__ hq_out,
    float* __restrict__ oas, float* __restrict__ oad, int N) {
    const size_t NS = (size_t)N * 32;
    const int tid = threadIdx.x;
    const int nbase = blockIdx.x * 64;
    const int lane = tid & 63, w = tid >> 6;
    const int l15 = lane & 15, quad = lane >> 4;
    const int koff = quad * 8;

    float av[8], dv[8];
    #pragma unroll
    for (int c = 0; c < 8; ++c) {
        av[c] = asrc[c * 16 + l15];
        dv[c] = adst[c * 16 + l15];
    }

    f32x4 acc[8];
    #pragma unroll
    for (int c = 0; c < 8; ++c) acc[c] = (f32x4)(0.f);

    const int g0 = nbase + w * 16 + l15;
    #pragma unroll
    for (int ks = 0; ks < 4; ++ks) {
        bf16x8 a0 = (bf16x8)(short)0;
        if (g0 < N) a0 = *(const bf16x8*)&Aq[(size_t)ks * NS + (size_t)g0 * 32 + koff];
        #pragma unroll
        for (int c = 0; c < 8; ++c) {
            bf16x8 b = *(const bf16x8*)&Wt[(size_t)(c * 16 + l15) * HD + ks * 32 + koff];
            acc[c] = __builtin_amdgcn_mfma_f32_16x16x32_bf16(a0, b, acc[c], 0, 0, 0);
        }
    }

    // D layout: row = quad*4 + reg, col = c*16 + l15 -> plane c>>1
    const int rowb = nbase + w * 16 + quad * 4;
    #pragma unroll
    for (int c = 0; c < 8; ++c) {
        f32x4 v = acc[c];
        const int p = c >> 1;
        const int coff = (c & 1) * 16 + l15;
        #pragma unroll
        for (int r = 0; r < 4; ++r) {
            int row = rowb + r;
            if (row < N) hq_out[(size_t)p * NS + (size_t)row * 32 + coff] = f2bf(v[r]);
        }
    }
    #pragma unroll
    for (int r = 0; r < 4; ++r) {
        float ps0 = 0.f, ps1 = 0.f, pd0 = 0.f, pd1 = 0.f;
        #pragma unroll
        for (int c = 0; c < 4; ++c) {
            float hv = acc[c][r];
            ps0 += hv * av[c]; pd0 += hv * dv[c];
        }
        #pragma unroll
        for (int c = 4; c < 8; ++c) {
            float hv = acc[c][r];
            ps1 += hv * av[c]; pd1 += hv * dv[c];
        }
        #pragma unroll
        for (int off = 1; off < 16; off <<= 1) {
            ps0 += __shfl_xor(ps0, off);
            ps1 += __shfl_xor(ps1, off);
            pd0 += __shfl_xor(pd0, off);
            pd1 += __shfl_xor(pd1, off);
        }
        int row = rowb + r;
        if (l15 == 0 && row < N) {
            *(float2*)&oas[row * 2] = make_float2(ps0, ps1);
            *(float2*)&oad[row * 2] = make_float2(pd0, pd1);
        }
    }
}

// ---------------- pooling (fused graph-size count) ----------------
__global__ void k_pool(const unsigned short* __restrict__ feat, const int* __restrict__ batch,
                       float* __restrict__ pooled, int* __restrict__ gcount, int N) {
    int col = threadIdx.x;
    int n0 = blockIdx.x * 128;
    int n1 = min(n0 + 128, N);
    float acc = 0.f;
    int curg = -1, runlen = 0;
    for (int n = n0; n < n1; ++n) {
        int g = batch[n];
        if (g != curg) {
            if (curg >= 0) {
                atomicAdd(&pooled[curg * HD + col], acc);
                if (col == 0) atomicAdd(&gcount[curg], runlen);
            }
            acc = 0.f; runlen = 0;
            curg = g;
        }
        acc += bf2f(feat[(size_t)n * HD + col]);
        runlen++;
    }
    if (curg >= 0) {
        atomicAdd(&pooled[curg * HD + col], acc);
        if (col == 0) atomicAdd(&gcount[curg], runlen);
    }
}

__global__ void k_final(const float* __restrict__ pooled, const int* __restrict__ gcount,
                        const float* __restrict__ lw, const float* __restrict__ lb,
                        float* __restrict__ out) {
    int tid = threadIdx.x;
    if (tid >= NGRAPH * NCLS) return;
    int g = tid / NCLS, c = tid % NCLS;
    float cnt = fmaxf((float)gcount[g], 1.f);
    const float* p = pooled + g * HD;
    float sum = 0.f;
    for (int k = 0; k < HD; ++k)
        sum += p[k] * lw[k * NCLS + c];
    float z = lb[c] + sum / cnt;
    out[tid] = 1.f / (1.f + __expf(-z));
}

// ---------------- launch ----------------

static inline size_t al256(size_t x) { return (x + 255) & ~(size_t)255; }

extern "C" void kernel_launch(void* const* d_in, const int* in_sizes, int n_in,
                              void* d_out, int out_size, void* d_ws, size_t ws_size,
                              hipStream_t stream) {
    const int N = in_sizes[0] / 4;   // x is [N,4]
    const int E = in_sizes[1] / 2;   // edge_index is [2,E]

    const float* x     = (const float*)d_in[0];
    const int*   esrc  = (const int*)d_in[1];
    const int*   edst  = esrc + E;
    const int*   batch = (const int*)d_in[2];
    const float* Wl[4]  = {(const float*)d_in[3],  (const float*)d_in[7],
                           (const float*)d_in[11], (const float*)d_in[15]};
    const float* asr[4] = {(const float*)d_in[4],  (const float*)d_in[8],
                           (const float*)d_in[12], (const float*)d_in[16]};
    const float* ads[4] = {(const float*)d_in[5],  (const float*)d_in[9],
                           (const float*)d_in[13], (const float*)d_in[17]};
    const float* bs[4]  = {(const float*)d_in[6],  (const float*)d_in[10],
                           (const float*)d_in[14], (const float*)d_in[18]};
    const float* lin_w = (const float*)d_in[19];
    const float* lin_b = (const float*)d_in[20];
    float* out = (float*)d_out;

    // workspace layout (zero-region first)
    char* w = (char*)d_ws;
    size_t off = 0;
    auto alloc = [&](size_t bytes) -> void* {
        void* p = w + off;
        off = al256(off + bytes);
        return p;
    };
    int*   deg    = (int*)alloc((size_t)N * 4);
    int*   fill   = (int*)alloc((size_t)N * 4);
    int*   gcount = (int*)alloc((size_t)NGRAPH * 4);
    float* pooled = (float*)alloc((size_t)NGRAPH * HD * 4);
    size_t zbytes = off;
    int*   ptr    = (int*)alloc((size_t)(N + 1) * 4);
    int*   bsum   = (int*)alloc((size_t)1024 * 4);
    int*   csr    = (int*)alloc((size_t)E * 4);
    int*   dstE   = (int*)alloc((size_t)E * 4);
    float* expE   = (float*)alloc((size_t)E * 2 * 4);
    float* invL   = (float*)alloc((size_t)N * 2 * 4);
    unsigned short* P1   = (unsigned short*)alloc((size_t)N * HD * 2);  // h (quartered)
    unsigned short* P2   = (unsigned short*)alloc((size_t)N * HD * 2);  // agg (quartered)
    unsigned short* feat = (unsigned short*)alloc((size_t)N * HD * 2);  // final (row-major)
    unsigned short* Wt   = (unsigned short*)alloc((size_t)3 * HD * HD * 2);
    float* asA = (float*)alloc((size_t)N * 2 * 4);
    float* adA = (float*)alloc((size_t)N * 2 * 4);
    float* asB = (float*)alloc((size_t)N * 2 * 4);
    float* adB = (float*)alloc((size_t)N * 2 * 4);
    (void)ws_size; (void)n_in; (void)out_size;

    hipMemsetAsync(d_ws, 0, zbytes, stream);

    // weight prep + CSR by dst (reused by all 4 layers)
    k_prepw<<<(3 * HD * HD + 255) / 256, 256, 0, stream>>>(Wl[1], Wl[2], Wl[3], Wt);
    k_deg<<<(E + 255) / 256, 256, 0, stream>>>(edst, deg, E);
    const int SB = (N + 2047) / 2048;
    k_scan_local<<<SB, 256, 0, stream>>>(deg, ptr, bsum, N);
    k_scan_bsum<<<1, 64, 0, stream>>>(bsum, SB);
    k_scan_add<<<SB, 256, 0, stream>>>(ptr, bsum, N);
    k_scatter<<<(E + 255) / 256, 256, 0, stream>>>(esrc, edst, ptr, fill, csr, dstE, E);

    const int eblk = (E + 255) / 256;
    const int tblk = (N * 4 + 255) / 256;            // 4-lane teams
    const dim3 gq((N + 63) / 64, 4);                 // gather: 64 nodes x 4 quarters

    // layer 1 gemm + alpha -> P1 (quartered), asA/adA
    k_gemm1_alpha<<<(N + 3) / 4, 256, 0, stream>>>(
        x, Wl[0], asr[0], ads[0], P1, asA, adA, N);

    const float* cas = asA; const float* cad = adA;
    float* nas = asB;       float* nad = adB;
    for (int i = 0; i < 4; ++i) {
        // per-edge attention for layer i
        k_edge_exp<<<eblk, 256, 0, stream>>>(csr, dstE, cas, cad, expE, E);
        k_node_inv<<<tblk, 256, 0, stream>>>(ptr, expE, invL, N);
        if (i < 3) {
            // aggregate (quartered) then GEMM layer i+1 (quartered in/out)
            k_gather_q<<<gq, 256, 0, stream>>>(
                P1, expE, invL, ptr, csr, bs[i], P2, (unsigned short*)nullptr, 0, N);
            k_gemm_mfma<<<(N + 63) / 64, 256, 0, stream>>>(
                P2, Wt + (size_t)i * HD * HD, asr[i + 1], ads[i + 1],
                P1, nas, nad, N);
            // swap alpha buffers
            const float* ts = cas; cas = nas; nas = (float*)ts;
            const float* td = cad; cad = nad; nad = (float*)td;
        } else {
            // final aggregate -> feat (row-major)
            k_gather_q<<<gq, 256, 0, stream>>>(
                P1, expE, invL, ptr, csr, bs[i], (unsigned short*)nullptr, feat, 1, N);
        }
    }

    k_pool<<<(N + 127) / 128, 128, 0, stream>>>(feat, batch, pooled, gcount, N);
    k_final<<<1, 320, 0, stream>>>(pooled, gcount, lin_w, lin_b, out);
}

// Round 8
// 357.475 us; speedup vs baseline: 1.6960x; 1.6960x over previous
//
#include <hip/hip_runtime.h>
#include <math.h>

// Problem constants (from reference)
#define NHEAD 2
#define NDIM  64
#define HD    128   // NHEAD*NDIM
#define NGRAPH 64
#define NCLS  5
#define NEG_SLOPE 0.2f
#define LDA 136   // padded LDS row stride (elements)

typedef __attribute__((ext_vector_type(8))) short bf16x8;
typedef __attribute__((ext_vector_type(4))) float f32x4;

static __device__ __forceinline__ unsigned short f2bf(float f) {
    unsigned int u = __float_as_uint(f);
    u = (u + 0x7fff + ((u >> 16) & 1)) >> 16;   // round-to-nearest-even
    return (unsigned short)u;
}
static __device__ __forceinline__ float bf2f(unsigned short b) {
    return __uint_as_float((unsigned int)b << 16);
}

// ---------------- CSR build ----------------

__global__ void k_deg(const int* __restrict__ dst, int* __restrict__ deg, int E) {
    int i = blockIdx.x * blockDim.x + threadIdx.x;
    if (i < E) atomicAdd(&deg[dst[i]], 1);
}

__global__ __launch_bounds__(256) void k_scan_local(const int* __restrict__ deg,
                                                    int* __restrict__ ptr,
                                                    int* __restrict__ bsum, int n) {
    __shared__ int wsum[4];
    const int tid = threadIdx.x, lane = tid & 63, wid = tid >> 6;
    const int base = blockIdx.x * 2048 + tid * 8;
    int v[8];
    #pragma unroll
    for (int k = 0; k < 8; ++k) {
        int i = base + k;
        v[k] = (i < n) ? deg[i] : 0;
    }
    #pragma unroll
    for (int k = 1; k < 8; ++k) v[k] += v[k - 1];
    int x = v[7];
    #pragma unroll
    for (int off = 1; off < 64; off <<= 1) {
        int t = __shfl_up(x, off, 64);
        if (lane >= off) x += t;
    }
    if (lane == 63) wsum[wid] = x;
    __syncthreads();
    int woff = 0;
    #pragma unroll
    for (int k = 0; k < 4; ++k) woff += (k < wid) ? wsum[k] : 0;
    int texcl = woff + x - v[7];
    #pragma unroll
    for (int k = 0; k < 8; ++k) {
        int i = base + k;
        if (i < n) ptr[i + 1] = texcl + v[k];
    }
    if (tid == 255) bsum[blockIdx.x] = woff + x;
    if (blockIdx.x == 0 && tid == 0) ptr[0] = 0;
}

__global__ void k_scan_bsum(int* __restrict__ bsum, int B) {
    int lane = threadIdx.x;
    int carry = 0;
    for (int base = 0; base < B; base += 64) {
        int i = base + lane;
        int v = (i < B) ? bsum[i] : 0;
        int x = v;
        #pragma unroll
        for (int off = 1; off < 64; off <<= 1) {
            int t = __shfl_up(x, off, 64);
            if (lane >= off) x += t;
        }
        if (i < B) bsum[i] = carry + x - v;
        carry += __shfl(x, 63, 64);
    }
}

__global__ __launch_bounds__(256) void k_scan_add(int* __restrict__ ptr,
                                                  const int* __restrict__ bsum, int n) {
    int off = bsum[blockIdx.x];
    if (off == 0) return;
    const int base = blockIdx.x * 2048 + threadIdx.x * 8;
    #pragma unroll
    for (int k = 0; k < 8; ++k) {
        int i = base + k;
        if (i < n) ptr[i + 1] += off;
    }
}

__global__ void k_scatter(const int* __restrict__ src, const int* __restrict__ dst,
                          const int* __restrict__ ptr, int* __restrict__ fill,
                          int* __restrict__ csr, int E) {
    int i = blockIdx.x * blockDim.x + threadIdx.x;
    if (i < E) {
        int d = dst[i];
        int pos = atomicAdd(&fill[d], 1);
        csr[ptr[d] + pos] = src[i];
    }
}

// ---------------- weight prep: fp32 W[k][n] -> bf16 Wt[n][k] for layers 2-4 ------

__global__ void k_prepw(const float* __restrict__ W2, const float* __restrict__ W3,
                        const float* __restrict__ W4, unsigned short* __restrict__ Wt) {
    int idx = blockIdx.x * blockDim.x + threadIdx.x;
    if (idx >= 3 * HD * HD) return;
    int l = idx / (HD * HD), rem = idx % (HD * HD);
    int n = rem >> 7, k = rem & 127;
    const float* W = (l == 0) ? W2 : (l == 1) ? W3 : W4;
    Wt[idx] = f2bf(W[k * HD + n]);
}

// ---------------- layer 1: x[N,4] @ W[4,128] + fused alpha dots ----------------
__global__ void k_gemm1_alpha(const float* __restrict__ x, const float* __restrict__ W,
                              const float* __restrict__ asrc, const float* __restrict__ adst,
                              unsigned short* __restrict__ out, float* __restrict__ oas,
                              float* __restrict__ oad, int N) {
    int n = (blockIdx.x * blockDim.x + threadIdx.x) >> 6;
    int lane = threadIdx.x & 63;
    if (n >= N) return;
    float4 xv = *(const float4*)&x[n * 4];
    int c0 = lane * 2;
    float2 w0 = *(const float2*)&W[c0];
    float2 w1 = *(const float2*)&W[128 + c0];
    float2 w2 = *(const float2*)&W[256 + c0];
    float2 w3 = *(const float2*)&W[384 + c0];
    float v0 = xv.x * w0.x + xv.y * w1.x + xv.z * w2.x + xv.w * w3.x;
    float v1 = xv.x * w0.y + xv.y * w1.y + xv.z * w2.y + xv.w * w3.y;
    unsigned short b0 = f2bf(v0), b1 = f2bf(v1);
    unsigned int packed = (unsigned int)b0 | ((unsigned int)b1 << 16);
    *(unsigned int*)&out[(size_t)n * HD + c0] = packed;
    float vx = bf2f(b0), vy = bf2f(b1);
    float2 av = *(const float2*)&asrc[c0];
    float2 dv = *(const float2*)&adst[c0];
    float s = vx * av.x + vy * av.y;
    float t = vx * dv.x + vy * dv.y;
    #pragma unroll
    for (int off = 16; off > 0; off >>= 1) {
        s += __shfl_xor(s, off);
        t += __shfl_xor(t, off);
    }
    if ((lane & 31) == 0) {
        int head = lane >> 5;
        oas[n * 2 + head] = s;
        oad[n * 2 + head] = t;
    }
}

// ---------------- per-node inverse softmax denominator (both heads) ----------
// 4-lane team per node; per edge: csr load + 8B gather from the L2-resident
// 400KB oas pool; exp recomputed identically in the agg kernels.
__global__ __launch_bounds__(256) void k_node_inv(const int* __restrict__ ptr,
                                                  const int* __restrict__ csr,
                                                  const float* __restrict__ oas,
                                                  const float* __restrict__ oad,
                                                  float* __restrict__ invL, int N) {
    int t = blockIdx.x * blockDim.x + threadIdx.x;
    int n = t >> 2, l4 = t & 3;
    if (n >= N) return;
    int beg = ptr[n], end = ptr[n + 1];
    float2 ad2 = *(const float2*)&oad[n * 2];
    float s0 = 0.f, s1 = 0.f;
    for (int j = beg + l4; j < end; j += 4) {
        int s = csr[j];
        float2 as2 = *(const float2*)&oas[s * 2];
        float e0 = as2.x + ad2.x; e0 = (e0 >= 0.f) ? e0 : NEG_SLOPE * e0;
        float e1 = as2.y + ad2.y; e1 = (e1 >= 0.f) ? e1 : NEG_SLOPE * e1;
        e0 = fminf(e0, 80.f); e1 = fminf(e1, 80.f);
        s0 += __expf(e0); s1 += __expf(e1);
    }
    s0 += __shfl_xor(s0, 1); s0 += __shfl_xor(s0, 2);
    s1 += __shfl_xor(s1, 1); s1 += __shfl_xor(s1, 2);
    if (l4 == 0)
        *(float2*)&invL[n * 2] = make_float2(1.f / (s0 + 1e-16f), 1.f / (s1 + 1e-16f));
}

// ---------------- agg body: pure gather+FMA, precomputed alpha ----------------
// Quarter-wave (16 lanes) per node; lane covers dims sub*8..sub*8+8 (head=sub>>3).
// Per edge: broadcast csr + broadcast oas (L2-resident), ~6 VALU for alpha,
// one 16B slice of the 256B row gather. 4-edge chunks for memory parallelism.
// No shuffles, no reductions, no early returns (barrier-safe).
static __device__ __forceinline__ void agg_acc(
    const unsigned short* __restrict__ h, const float* __restrict__ oas,
    const float* __restrict__ oad, const float* __restrict__ invL,
    const int* __restrict__ ptr, const int* __restrict__ csr,
    int n, int N, int sub, int hsel, float* acc) {
    #pragma unroll
    for (int k = 0; k < 8; ++k) acc[k] = 0.f;
    if (n >= N) return;
    const int beg = ptr[n], end = ptr[n + 1];
    const float adh = oad[n * 2 + hsel];
    const float inv = invL[n * 2 + hsel];

    auto alpha = [&](float as) {
        float e = as + adh;
        e = (e >= 0.f) ? e : NEG_SLOPE * e;
        e = fminf(e, 80.f);
        return __expf(e) * inv;
    };
    auto accum = [&](uint4 hv, float a) {
        #pragma unroll
        for (int k = 0; k < 4; ++k) {
            unsigned int u = (&hv.x)[k];
            acc[2 * k]     += a * __uint_as_float(u << 16);
            acc[2 * k + 1] += a * __uint_as_float(u & 0xffff0000u);
        }
    };

    int j = beg;
    for (; j + 4 <= end; j += 4) {
        int s0 = csr[j], s1 = csr[j + 1], s2 = csr[j + 2], s3 = csr[j + 3];
        uint4 h0 = *(const uint4*)&h[(size_t)s0 * HD + sub * 8];
        uint4 h1 = *(const uint4*)&h[(size_t)s1 * HD + sub * 8];
        uint4 h2 = *(const uint4*)&h[(size_t)s2 * HD + sub * 8];
        uint4 h3 = *(const uint4*)&h[(size_t)s3 * HD + sub * 8];
        float x0 = oas[s0 * 2 + hsel], x1 = oas[s1 * 2 + hsel];
        float x2 = oas[s2 * 2 + hsel], x3 = oas[s3 * 2 + hsel];
        accum(h0, alpha(x0));
        accum(h1, alpha(x1));
        accum(h2, alpha(x2));
        accum(h3, alpha(x3));
    }
    for (; j < end; ++j) {
        int s = csr[j];
        uint4 hv = *(const uint4*)&h[(size_t)s * HD + sub * 8];
        float xs = oas[s * 2 + hsel];
        accum(hv, alpha(xs));
    }
}

static __device__ __forceinline__ uint4 bias_relu_pack(
    const float* acc, const float* __restrict__ bias, int sub) {
    float4 ba = *(const float4*)&bias[sub * 8];
    float4 bb = *(const float4*)&bias[sub * 8 + 4];
    float o[8];
    o[0] = fmaxf(acc[0] + ba.x, 0.f);
    o[1] = fmaxf(acc[1] + ba.y, 0.f);
    o[2] = fmaxf(acc[2] + ba.z, 0.f);
    o[3] = fmaxf(acc[3] + ba.w, 0.f);
    o[4] = fmaxf(acc[4] + bb.x, 0.f);
    o[5] = fmaxf(acc[5] + bb.y, 0.f);
    o[6] = fmaxf(acc[6] + bb.z, 0.f);
    o[7] = fmaxf(acc[7] + bb.w, 0.f);
    uint4 pk;
    pk.x = (unsigned int)f2bf(o[0]) | ((unsigned int)f2bf(o[1]) << 16);
    pk.y = (unsigned int)f2bf(o[2]) | ((unsigned int)f2bf(o[3]) << 16);
    pk.z = (unsigned int)f2bf(o[4]) | ((unsigned int)f2bf(o[5]) << 16);
    pk.w = (unsigned int)f2bf(o[6]) | ((unsigned int)f2bf(o[7]) << 16);
    return pk;
}

// ---------------- fused layer: agg(l) -> LDS -> gemm(l+1) + alpha ----------
// 16 nodes/block (quarter-wave per node, round-6 verified geometry).
// GEMM col-split across waves; output staged in LDS and written as full
// coalesced 256B rows (fixes round-6's 2.7x write amplification).
__global__ __launch_bounds__(256, 8) void k_agg_gemm(
    const unsigned short* __restrict__ hin,
    const float* __restrict__ oas_in, const float* __restrict__ oad_in,
    const float* __restrict__ invL,
    const int* __restrict__ ptr, const int* __restrict__ csr,
    const float* __restrict__ bias,             // agg bias (layer l)
    const unsigned short* __restrict__ Wt,      // layer l+1 weight, [n][k] bf16
    const float* __restrict__ asrc, const float* __restrict__ adst,  // layer l+1
    unsigned short* __restrict__ hout,
    float* __restrict__ oas_out, float* __restrict__ oad_out, int N) {
    __shared__ unsigned short As[16 * LDA];
    __shared__ unsigned short Ot[16][HD];
    __shared__ float psL[4][16], pdL[4][16];
    const int tid = threadIdx.x;
    const int lane = tid & 63, w = tid >> 6;
    const int grp = lane >> 4, sub = lane & 15;
    const int hsel = sub >> 3;
    const int nbase = blockIdx.x * 16;

    // ---- agg phase ----
    const int row = w * 4 + grp;
    float acc8[8];
    agg_acc(hin, oas_in, oad_in, invL, ptr, csr, nbase + row, N, sub, hsel, acc8);
    uint4 pk = bias_relu_pack(acc8, bias, sub);
    *(uint4*)&As[(size_t)row * LDA + sub * 8] = pk;
    __syncthreads();

    // ---- gemm phase: wave w owns cols c in {2w, 2w+1} ----
    float av2[2], dv2[2];
    #pragma unroll
    for (int i = 0; i < 2; ++i) {
        int c = w * 2 + i;
        av2[i] = asrc[c * 16 + sub];
        dv2[i] = adst[c * 16 + sub];
    }
    f32x4 acc[2];
    acc[0] = (f32x4)(0.f);
    acc[1] = (f32x4)(0.f);
    #pragma unroll
    for (int ks = 0; ks < 4; ++ks) {
        bf16x8 a0 = *(const bf16x8*)&As[(size_t)sub * LDA + ks * 32 + grp * 8];
        #pragma unroll
        for (int i = 0; i < 2; ++i) {
            int c = w * 2 + i;
            bf16x8 b = *(const bf16x8*)&Wt[(size_t)(c * 16 + sub) * HD + ks * 32 + grp * 8];
            acc[i] = __builtin_amdgcn_mfma_f32_16x16x32_bf16(a0, b, acc[i], 0, 0, 0);
        }
    }

    // stage output tile (D: row = grp*4 + r, col = c*16 + sub)
    #pragma unroll
    for (int i = 0; i < 2; ++i) {
        int col = (w * 2 + i) * 16 + sub;
        #pragma unroll
        for (int r = 0; r < 4; ++r)
            Ot[grp * 4 + r][col] = f2bf(acc[i][r]);
    }
    // alpha partials (each wave covers half of one head's 64 cols)
    #pragma unroll
    for (int r = 0; r < 4; ++r) {
        float ps = acc[0][r] * av2[0] + acc[1][r] * av2[1];
        float pd = acc[0][r] * dv2[0] + acc[1][r] * dv2[1];
        #pragma unroll
        for (int off = 1; off < 16; off <<= 1) {
            ps += __shfl_xor(ps, off);
            pd += __shfl_xor(pd, off);
        }
        if (sub == 0) {
            psL[w][grp * 4 + r] = ps;
            pdL[w][grp * 4 + r] = pd;
        }
    }
    __syncthreads();

    // coalesced full-row writes: thread t -> row t>>4, 16B chunk t&15
    {
        int r2 = tid >> 4, c16 = tid & 15;
        int gn = nbase + r2;
        if (gn < N) {
            uint4 v = *(const uint4*)&Ot[r2][c16 * 8];
            *(uint4*)&hout[(size_t)gn * HD + c16 * 8] = v;
        }
    }
    if (tid < 32) {
        int r2 = tid & 15, head = tid >> 4;
        int n2 = nbase + r2;
        if (n2 < N) {
            float s = psL[2 * head][r2] + psL[2 * head + 1][r2];
            float d = pdL[2 * head][r2] + pdL[2 * head + 1][r2];
            oas_out[n2 * 2 + head] = s;
            oad_out[n2 * 2 + head] = d;
        }
    }
}

// ---------------- final agg (layer 4): writes feat to global ----------------
__global__ __launch_bounds__(256) void k_agg_final(
    const unsigned short* __restrict__ hin,
    const float* __restrict__ oas_in, const float* __restrict__ oad_in,
    const float* __restrict__ invL,
    const int* __restrict__ ptr, const int* __restrict__ csr,
    const float* __restrict__ bias,
    unsigned short* __restrict__ out, int N) {
    const int tid = threadIdx.x;
    const int lane = tid & 63;
    const int grp = lane >> 4, sub = lane & 15;
    const int hsel = sub >> 3;
    const int n = ((blockIdx.x * blockDim.x + tid) >> 6) * 4 + grp;
    float acc8[8];
    agg_acc(hin, oas_in, oad_in, invL, ptr, csr, n, N, sub, hsel, acc8);
    if (n < N) {
        uint4 pk = bias_relu_pack(acc8, bias, sub);
        *(uint4*)&out[(size_t)n * HD + sub * 8] = pk;
    }
}

// ---------------- pooling (fused graph-size count) ----------------
__global__ void k_pool(const unsigned short* __restrict__ feat, const int* __restrict__ batch,
                       float* __restrict__ pooled, int* __restrict__ gcount, int N) {
    int col = threadIdx.x;
    int n0 = blockIdx.x * 128;
    int n1 = min(n0 + 128, N);
    float acc = 0.f;
    int curg = -1, runlen = 0;
    for (int n = n0; n < n1; ++n) {
        int g = batch[n];
        if (g != curg) {
            if (curg >= 0) {
                atomicAdd(&pooled[curg * HD + col], acc);
                if (col == 0) atomicAdd(&gcount[curg], runlen);
            }
            acc = 0.f; runlen = 0;
            curg = g;
        }
        acc += bf2f(feat[(size_t)n * HD + col]);
        runlen++;
    }
    if (curg >= 0) {
        atomicAdd(&pooled[curg * HD + col], acc);
        if (col == 0) atomicAdd(&gcount[curg], runlen);
    }
}

__global__ void k_final(const float* __restrict__ pooled, const int* __restrict__ gcount,
                        const float* __restrict__ lw, const float* __restrict__ lb,
                        float* __restrict__ out) {
    int tid = threadIdx.x;
    if (tid >= NGRAPH * NCLS) return;
    int g = tid / NCLS, c = tid % NCLS;
    float cnt = fmaxf((float)gcount[g], 1.f);
    const float* p = pooled + g * HD;
    float sum = 0.f;
    for (int k = 0; k < HD; ++k)
        sum += p[k] * lw[k * NCLS + c];
    float z = lb[c] + sum / cnt;
    out[tid] = 1.f / (1.f + __expf(-z));
}

// ---------------- launch ----------------

static inline size_t al256(size_t x) { return (x + 255) & ~(size_t)255; }

extern "C" void kernel_launch(void* const* d_in, const int* in_sizes, int n_in,
                              void* d_out, int out_size, void* d_ws, size_t ws_size,
                              hipStream_t stream) {
    const int N = in_sizes[0] / 4;   // x is [N,4]
    const int E = in_sizes[1] / 2;   // edge_index is [2,E]

    const float* x     = (const float*)d_in[0];
    const int*   esrc  = (const int*)d_in[1];
    const int*   edst  = esrc + E;
    const int*   batch = (const int*)d_in[2];
    const float* Wl[4]  = {(const float*)d_in[3],  (const float*)d_in[7],
                           (const float*)d_in[11], (const float*)d_in[15]};
    const float* asr[4] = {(const float*)d_in[4],  (const float*)d_in[8],
                           (const float*)d_in[12], (const float*)d_in[16]};
    const float* ads[4] = {(const float*)d_in[5],  (const float*)d_in[9],
                           (const float*)d_in[13], (const float*)d_in[17]};
    const float* bs[4]  = {(const float*)d_in[6],  (const float*)d_in[10],
                           (const float*)d_in[14], (const float*)d_in[18]};
    const float* lin_w = (const float*)d_in[19];
    const float* lin_b = (const float*)d_in[20];
    float* out = (float*)d_out;

    // workspace layout (zero-region first)
    char* w = (char*)d_ws;
    size_t off = 0;
    auto alloc = [&](size_t bytes) -> void* {
        void* p = w + off;
        off = al256(off + bytes);
        return p;
    };
    int*   deg    = (int*)alloc((size_t)N * 4);
    int*   fill   = (int*)alloc((size_t)N * 4);
    int*   gcount = (int*)alloc((size_t)NGRAPH * 4);
    float* pooled = (float*)alloc((size_t)NGRAPH * HD * 4);
    size_t zbytes = off;
    int*   ptr    = (int*)alloc((size_t)(N + 1) * 4);
    int*   bsum   = (int*)alloc((size_t)1024 * 4);
    int*   csr    = (int*)alloc((size_t)E * 4);
    float* invL   = (float*)alloc((size_t)N * 2 * 4);
    unsigned short* hA   = (unsigned short*)alloc((size_t)N * HD * 2);
    unsigned short* hB   = (unsigned short*)alloc((size_t)N * HD * 2);
    unsigned short* feat = (unsigned short*)alloc((size_t)N * HD * 2);
    unsigned short* Wt   = (unsigned short*)alloc((size_t)3 * HD * HD * 2);
    float* asA = (float*)alloc((size_t)N * 2 * 4);
    float* adA = (float*)alloc((size_t)N * 2 * 4);
    float* asB = (float*)alloc((size_t)N * 2 * 4);
    float* adB = (float*)alloc((size_t)N * 2 * 4);
    (void)ws_size; (void)n_in; (void)out_size;

    hipMemsetAsync(d_ws, 0, zbytes, stream);

    // weight prep + CSR by dst (reused by all 4 layers)
    k_prepw<<<(3 * HD * HD + 255) / 256, 256, 0, stream>>>(Wl[1], Wl[2], Wl[3], Wt);
    k_deg<<<(E + 255) / 256, 256, 0, stream>>>(edst, deg, E);
    const int SB = (N + 2047) / 2048;
    k_scan_local<<<SB, 256, 0, stream>>>(deg, ptr, bsum, N);
    k_scan_bsum<<<1, 64, 0, stream>>>(bsum, SB);
    k_scan_add<<<SB, 256, 0, stream>>>(ptr, bsum, N);
    k_scatter<<<(E + 255) / 256, 256, 0, stream>>>(esrc, edst, ptr, fill, csr, E);

    const int tblk = (N * 4 + 255) / 256;     // 4-lane teams (node_inv)
    const int fblk = (N + 15) / 16;           // 16 nodes/block

    // layer 1 gemm + alpha -> hA, asA/adA
    k_gemm1_alpha<<<(N + 3) / 4, 256, 0, stream>>>(
        x, Wl[0], asr[0], ads[0], hA, asA, adA, N);

    const unsigned short* hc = hA; unsigned short* hn = hB;
    const float* cas = asA; const float* cad = adA;
    float* nas = asB;       float* nad = adB;
    for (int i = 0; i < 4; ++i) {
        k_node_inv<<<tblk, 256, 0, stream>>>(ptr, csr, cas, cad, invL, N);
        if (i < 3) {
            k_agg_gemm<<<fblk, 256, 0, stream>>>(
                hc, cas, cad, invL, ptr, csr, bs[i],
                Wt + (size_t)i * HD * HD, asr[i + 1], ads[i + 1],
                hn, nas, nad, N);
            // swap
            const unsigned short* th = hc; hc = hn; hn = (unsigned short*)th;
            const float* ts = cas; cas = nas; nas = (float*)ts;
            const float* td = cad; cad = nad; nad = (float*)td;
        } else {
            k_agg_final<<<fblk, 256, 0, stream>>>(
                hc, cas, cad, invL, ptr, csr, bs[i], feat, N);
        }
    }

    k_pool<<<(N + 127) / 128, 128, 0, stream>>>(feat, batch, pooled, gcount, N);
    k_final<<<1, 320, 0, stream>>>(pooled, gcount, lin_w, lin_b, out);
}

// Round 9
// 337.945 us; speedup vs baseline: 1.7940x; 1.0578x over previous
//
#include <hip/hip_runtime.h>
#include <math.h>

// Problem constants (from reference)
#define NHEAD 2
#define NDIM  64
#define HD    128   // NHEAD*NDIM
#define NGRAPH 64
#define NCLS  5
#define NEG_SLOPE 0.2f
#define LDA 136   // padded LDS row stride (elements)

typedef __attribute__((ext_vector_type(8))) short bf16x8;
typedef __attribute__((ext_vector_type(4))) float f32x4;

static __device__ __forceinline__ unsigned short f2bf(float f) {
    unsigned int u = __float_as_uint(f);
    u = (u + 0x7fff + ((u >> 16) & 1)) >> 16;   // round-to-nearest-even
    return (unsigned short)u;
}
static __device__ __forceinline__ float bf2f(unsigned short b) {
    return __uint_as_float((unsigned int)b << 16);
}

// ---------------- CSR build ----------------

__global__ void k_deg(const int* __restrict__ dst, int* __restrict__ deg, int E) {
    int i = blockIdx.x * blockDim.x + threadIdx.x;
    if (i < E) atomicAdd(&deg[dst[i]], 1);
}

__global__ __launch_bounds__(256) void k_scan_local(const int* __restrict__ deg,
                                                    int* __restrict__ ptr,
                                                    int* __restrict__ bsum, int n) {
    __shared__ int wsum[4];
    const int tid = threadIdx.x, lane = tid & 63, wid = tid >> 6;
    const int base = blockIdx.x * 2048 + tid * 8;
    int v[8];
    #pragma unroll
    for (int k = 0; k < 8; ++k) {
        int i = base + k;
        v[k] = (i < n) ? deg[i] : 0;
    }
    #pragma unroll
    for (int k = 1; k < 8; ++k) v[k] += v[k - 1];
    int x = v[7];
    #pragma unroll
    for (int off = 1; off < 64; off <<= 1) {
        int t = __shfl_up(x, off, 64);
        if (lane >= off) x += t;
    }
    if (lane == 63) wsum[wid] = x;
    __syncthreads();
    int woff = 0;
    #pragma unroll
    for (int k = 0; k < 4; ++k) woff += (k < wid) ? wsum[k] : 0;
    int texcl = woff + x - v[7];
    #pragma unroll
    for (int k = 0; k < 8; ++k) {
        int i = base + k;
        if (i < n) ptr[i + 1] = texcl + v[k];
    }
    if (tid == 255) bsum[blockIdx.x] = woff + x;
    if (blockIdx.x == 0 && tid == 0) ptr[0] = 0;
}

__global__ void k_scan_bsum(int* __restrict__ bsum, int B) {
    int lane = threadIdx.x;
    int carry = 0;
    for (int base = 0; base < B; base += 64) {
        int i = base + lane;
        int v = (i < B) ? bsum[i] : 0;
        int x = v;
        #pragma unroll
        for (int off = 1; off < 64; off <<= 1) {
            int t = __shfl_up(x, off, 64);
            if (lane >= off) x += t;
        }
        if (i < B) bsum[i] = carry + x - v;
        carry += __shfl(x, 63, 64);
    }
}

__global__ __launch_bounds__(256) void k_scan_add(int* __restrict__ ptr,
                                                  const int* __restrict__ bsum, int n) {
    int off = bsum[blockIdx.x];
    if (off == 0) return;
    const int base = blockIdx.x * 2048 + threadIdx.x * 8;
    #pragma unroll
    for (int k = 0; k < 8; ++k) {
        int i = base + k;
        if (i < n) ptr[i + 1] += off;
    }
}

__global__ void k_scatter(const int* __restrict__ src, const int* __restrict__ dst,
                          const int* __restrict__ ptr, int* __restrict__ fill,
                          int* __restrict__ csr, int E) {
    int i = blockIdx.x * blockDim.x + threadIdx.x;
    if (i < E) {
        int d = dst[i];
        int pos = atomicAdd(&fill[d], 1);
        csr[ptr[d] + pos] = src[i];
    }
}

// ---------------- weight prep: fp32 W[k][n] -> bf16 Wt[n][k] for layers 2-4 ------

__global__ void k_prepw(const float* __restrict__ W2, const float* __restrict__ W3,
                        const float* __restrict__ W4, unsigned short* __restrict__ Wt) {
    int idx = blockIdx.x * blockDim.x + threadIdx.x;
    if (idx >= 3 * HD * HD) return;
    int l = idx / (HD * HD), rem = idx % (HD * HD);
    int n = rem >> 7, k = rem & 127;
    const float* W = (l == 0) ? W2 : (l == 1) ? W3 : W4;
    Wt[idx] = f2bf(W[k * HD + n]);
}

// ---------------- layer 1: x[N,4] @ W[4,128] + fused alpha dots ----------------
__global__ void k_gemm1_alpha(const float* __restrict__ x, const float* __restrict__ W,
                              const float* __restrict__ asrc, const float* __restrict__ adst,
                              unsigned short* __restrict__ out, float* __restrict__ oas,
                              float* __restrict__ oad, int N) {
    int n = (blockIdx.x * blockDim.x + threadIdx.x) >> 6;
    int lane = threadIdx.x & 63;
    if (n >= N) return;
    float4 xv = *(const float4*)&x[n * 4];
    int c0 = lane * 2;
    float2 w0 = *(const float2*)&W[c0];
    float2 w1 = *(const float2*)&W[128 + c0];
    float2 w2 = *(const float2*)&W[256 + c0];
    float2 w3 = *(const float2*)&W[384 + c0];
    float v0 = xv.x * w0.x + xv.y * w1.x + xv.z * w2.x + xv.w * w3.x;
    float v1 = xv.x * w0.y + xv.y * w1.y + xv.z * w2.y + xv.w * w3.y;
    unsigned short b0 = f2bf(v0), b1 = f2bf(v1);
    unsigned int packed = (unsigned int)b0 | ((unsigned int)b1 << 16);
    *(unsigned int*)&out[(size_t)n * HD + c0] = packed;
    float vx = bf2f(b0), vy = bf2f(b1);
    float2 av = *(const float2*)&asrc[c0];
    float2 dv = *(const float2*)&adst[c0];
    float s = vx * av.x + vy * av.y;
    float t = vx * dv.x + vy * dv.y;
    #pragma unroll
    for (int off = 16; off > 0; off >>= 1) {
        s += __shfl_xor(s, off);
        t += __shfl_xor(t, off);
    }
    if ((lane & 31) == 0) {
        int head = lane >> 5;
        oas[n * 2 + head] = s;
        oad[n * 2 + head] = t;
    }
}

// ---------------- agg body: UNNORMALIZED gather+FMA -------------------------
// Quarter-wave (16 lanes) per node; lane covers dims sub*8..sub*8+8 (head=sub>>3).
// acc = sum_j exp(e_j) * h_j ; denom = sum_j exp(e_j) (every lane computes the
// same exp chain for its head -> denominator costs 1 add/edge). Division by
// (denom + 1e-16) happens once in the epilogue -> no separate node_inv pass.
// No shuffles, no reductions, no early returns (barrier-safe).
static __device__ __forceinline__ void agg_acc(
    const unsigned short* __restrict__ h, const float* __restrict__ oas,
    const float* __restrict__ oad,
    const int* __restrict__ ptr, const int* __restrict__ csr,
    int n, int N, int sub, int hsel, float* acc, float& denom) {
    #pragma unroll
    for (int k = 0; k < 8; ++k) acc[k] = 0.f;
    denom = 0.f;
    if (n >= N) return;
    const int beg = ptr[n], end = ptr[n + 1];
    const float adh = oad[n * 2 + hsel];

    auto weight = [&](float as) {
        float e = as + adh;
        e = (e >= 0.f) ? e : NEG_SLOPE * e;
        e = fminf(e, 80.f);
        return __expf(e);
    };
    auto accum = [&](uint4 hv, float a) {
        denom += a;
        #pragma unroll
        for (int k = 0; k < 4; ++k) {
            unsigned int u = (&hv.x)[k];
            acc[2 * k]     += a * __uint_as_float(u << 16);
            acc[2 * k + 1] += a * __uint_as_float(u & 0xffff0000u);
        }
    };

    int j = beg;
    for (; j + 4 <= end; j += 4) {
        int s0 = csr[j], s1 = csr[j + 1], s2 = csr[j + 2], s3 = csr[j + 3];
        uint4 h0 = *(const uint4*)&h[(size_t)s0 * HD + sub * 8];
        uint4 h1 = *(const uint4*)&h[(size_t)s1 * HD + sub * 8];
        uint4 h2 = *(const uint4*)&h[(size_t)s2 * HD + sub * 8];
        uint4 h3 = *(const uint4*)&h[(size_t)s3 * HD + sub * 8];
        float x0 = oas[s0 * 2 + hsel], x1 = oas[s1 * 2 + hsel];
        float x2 = oas[s2 * 2 + hsel], x3 = oas[s3 * 2 + hsel];
        accum(h0, weight(x0));
        accum(h1, weight(x1));
        accum(h2, weight(x2));
        accum(h3, weight(x3));
    }
    for (; j < end; ++j) {
        int s = csr[j];
        uint4 hv = *(const uint4*)&h[(size_t)s * HD + sub * 8];
        float xs = oas[s * 2 + hsel];
        accum(hv, weight(xs));
    }
}

static __device__ __forceinline__ uint4 norm_bias_relu_pack(
    const float* acc, float denom, const float* __restrict__ bias, int sub) {
    float inv = 1.f / (denom + 1e-16f);
    float4 ba = *(const float4*)&bias[sub * 8];
    float4 bb = *(const float4*)&bias[sub * 8 + 4];
    float o[8];
    o[0] = fmaxf(acc[0] * inv + ba.x, 0.f);
    o[1] = fmaxf(acc[1] * inv + ba.y, 0.f);
    o[2] = fmaxf(acc[2] * inv + ba.z, 0.f);
    o[3] = fmaxf(acc[3] * inv + ba.w, 0.f);
    o[4] = fmaxf(acc[4] * inv + bb.x, 0.f);
    o[5] = fmaxf(acc[5] * inv + bb.y, 0.f);
    o[6] = fmaxf(acc[6] * inv + bb.z, 0.f);
    o[7] = fmaxf(acc[7] * inv + bb.w, 0.f);
    uint4 pk;
    pk.x = (unsigned int)f2bf(o[0]) | ((unsigned int)f2bf(o[1]) << 16);
    pk.y = (unsigned int)f2bf(o[2]) | ((unsigned int)f2bf(o[3]) << 16);
    pk.z = (unsigned int)f2bf(o[4]) | ((unsigned int)f2bf(o[5]) << 16);
    pk.w = (unsigned int)f2bf(o[6]) | ((unsigned int)f2bf(o[7]) << 16);
    return pk;
}

// ---------------- fused layer: agg(l) -> LDS -> gemm(l+1) + alpha ----------
// 16 nodes/block (quarter-wave per node). GEMM col-split across waves; output
// staged in LDS and written as full coalesced 256B rows.
__global__ __launch_bounds__(256, 8) void k_agg_gemm(
    const unsigned short* __restrict__ hin,
    const float* __restrict__ oas_in, const float* __restrict__ oad_in,
    const int* __restrict__ ptr, const int* __restrict__ csr,
    const float* __restrict__ bias,             // agg bias (layer l)
    const unsigned short* __restrict__ Wt,      // layer l+1 weight, [n][k] bf16
    const float* __restrict__ asrc, const float* __restrict__ adst,  // layer l+1
    unsigned short* __restrict__ hout,
    float* __restrict__ oas_out, float* __restrict__ oad_out, int N) {
    __shared__ unsigned short As[16 * LDA];
    __shared__ unsigned short Ot[16][HD];
    __shared__ float psL[4][16], pdL[4][16];
    const int tid = threadIdx.x;
    const int lane = tid & 63, w = tid >> 6;
    const int grp = lane >> 4, sub = lane & 15;
    const int hsel = sub >> 3;
    const int nbase = blockIdx.x * 16;

    // ---- agg phase ----
    const int row = w * 4 + grp;
    float acc8[8], denom;
    agg_acc(hin, oas_in, oad_in, ptr, csr, nbase + row, N, sub, hsel, acc8, denom);
    uint4 pk = norm_bias_relu_pack(acc8, denom, bias, sub);
    *(uint4*)&As[(size_t)row * LDA + sub * 8] = pk;
    __syncthreads();

    // ---- gemm phase: wave w owns cols c in {2w, 2w+1} ----
    float av2[2], dv2[2];
    #pragma unroll
    for (int i = 0; i < 2; ++i) {
        int c = w * 2 + i;
        av2[i] = asrc[c * 16 + sub];
        dv2[i] = adst[c * 16 + sub];
    }
    f32x4 acc[2];
    acc[0] = (f32x4)(0.f);
    acc[1] = (f32x4)(0.f);
    #pragma unroll
    for (int ks = 0; ks < 4; ++ks) {
        bf16x8 a0 = *(const bf16x8*)&As[(size_t)sub * LDA + ks * 32 + grp * 8];
        #pragma unroll
        for (int i = 0; i < 2; ++i) {
            int c = w * 2 + i;
            bf16x8 b = *(const bf16x8*)&Wt[(size_t)(c * 16 + sub) * HD + ks * 32 + grp * 8];
            acc[i] = __builtin_amdgcn_mfma_f32_16x16x32_bf16(a0, b, acc[i], 0, 0, 0);
        }
    }

    // stage output tile (D: row = grp*4 + r, col = c*16 + sub)
    #pragma unroll
    for (int i = 0; i < 2; ++i) {
        int col = (w * 2 + i) * 16 + sub;
        #pragma unroll
        for (int r = 0; r < 4; ++r)
            Ot[grp * 4 + r][col] = f2bf(acc[i][r]);
    }
    // alpha partials (each wave covers half of one head's 64 cols)
    #pragma unroll
    for (int r = 0; r < 4; ++r) {
        float ps = acc[0][r] * av2[0] + acc[1][r] * av2[1];
        float pd = acc[0][r] * dv2[0] + acc[1][r] * dv2[1];
        #pragma unroll
        for (int off = 1; off < 16; off <<= 1) {
            ps += __shfl_xor(ps, off);
            pd += __shfl_xor(pd, off);
        }
        if (sub == 0) {
            psL[w][grp * 4 + r] = ps;
            pdL[w][grp * 4 + r] = pd;
        }
    }
    __syncthreads();

    // coalesced full-row writes: thread t -> row t>>4, 16B chunk t&15
    {
        int r2 = tid >> 4, c16 = tid & 15;
        int gn = nbase + r2;
        if (gn < N) {
            uint4 v = *(const uint4*)&Ot[r2][c16 * 8];
            *(uint4*)&hout[(size_t)gn * HD + c16 * 8] = v;
        }
    }
    if (tid < 32) {
        int r2 = tid & 15, head = tid >> 4;
        int n2 = nbase + r2;
        if (n2 < N) {
            float s = psL[2 * head][r2] + psL[2 * head + 1][r2];
            float d = pdL[2 * head][r2] + pdL[2 * head + 1][r2];
            oas_out[n2 * 2 + head] = s;
            oad_out[n2 * 2 + head] = d;
        }
    }
}

// ---------------- final agg (layer 4): writes feat to global ----------------
__global__ __launch_bounds__(256) void k_agg_final(
    const unsigned short* __restrict__ hin,
    const float* __restrict__ oas_in, const float* __restrict__ oad_in,
    const int* __restrict__ ptr, const int* __restrict__ csr,
    const float* __restrict__ bias,
    unsigned short* __restrict__ out, int N) {
    const int tid = threadIdx.x;
    const int lane = tid & 63;
    const int grp = lane >> 4, sub = lane & 15;
    const int hsel = sub >> 3;
    const int n = ((blockIdx.x * blockDim.x + tid) >> 6) * 4 + grp;
    float acc8[8], denom;
    agg_acc(hin, oas_in, oad_in, ptr, csr, n, N, sub, hsel, acc8, denom);
    if (n < N) {
        uint4 pk = norm_bias_relu_pack(acc8, denom, bias, sub);
        *(uint4*)&out[(size_t)n * HD + sub * 8] = pk;
    }
}

// ---------------- pooling (fused graph-size count) ----------------
__global__ void k_pool(const unsigned short* __restrict__ feat, const int* __restrict__ batch,
                       float* __restrict__ pooled, int* __restrict__ gcount, int N) {
    int col = threadIdx.x;
    int n0 = blockIdx.x * 128;
    int n1 = min(n0 + 128, N);
    float acc = 0.f;
    int curg = -1, runlen = 0;
    for (int n = n0; n < n1; ++n) {
        int g = batch[n];
        if (g != curg) {
            if (curg >= 0) {
                atomicAdd(&pooled[curg * HD + col], acc);
                if (col == 0) atomicAdd(&gcount[curg], runlen);
            }
            acc = 0.f; runlen = 0;
            curg = g;
        }
        acc += bf2f(feat[(size_t)n * HD + col]);
        runlen++;
    }
    if (curg >= 0) {
        atomicAdd(&pooled[curg * HD + col], acc);
        if (col == 0) atomicAdd(&gcount[curg], runlen);
    }
}

__global__ void k_final(const float* __restrict__ pooled, const int* __restrict__ gcount,
                        const float* __restrict__ lw, const float* __restrict__ lb,
                        float* __restrict__ out) {
    int tid = threadIdx.x;
    if (tid >= NGRAPH * NCLS) return;
    int g = tid / NCLS, c = tid % NCLS;
    float cnt = fmaxf((float)gcount[g], 1.f);
    const float* p = pooled + g * HD;
    float sum = 0.f;
    for (int k = 0; k < HD; ++k)
        sum += p[k] * lw[k * NCLS + c];
    float z = lb[c] + sum / cnt;
    out[tid] = 1.f / (1.f + __expf(-z));
}

// ---------------- launch ----------------

static inline size_t al256(size_t x) { return (x + 255) & ~(size_t)255; }

extern "C" void kernel_launch(void* const* d_in, const int* in_sizes, int n_in,
                              void* d_out, int out_size, void* d_ws, size_t ws_size,
                              hipStream_t stream) {
    const int N = in_sizes[0] / 4;   // x is [N,4]
    const int E = in_sizes[1] / 2;   // edge_index is [2,E]

    const float* x     = (const float*)d_in[0];
    const int*   esrc  = (const int*)d_in[1];
    const int*   edst  = esrc + E;
    const int*   batch = (const int*)d_in[2];
    const float* Wl[4]  = {(const float*)d_in[3],  (const float*)d_in[7],
                           (const float*)d_in[11], (const float*)d_in[15]};
    const float* asr[4] = {(const float*)d_in[4],  (const float*)d_in[8],
                           (const float*)d_in[12], (const float*)d_in[16]};
    const float* ads[4] = {(const float*)d_in[5],  (const float*)d_in[9],
                           (const float*)d_in[13], (const float*)d_in[17]};
    const float* bs[4]  = {(const float*)d_in[6],  (const float*)d_in[10],
                           (const float*)d_in[14], (const float*)d_in[18]};
    const float* lin_w = (const float*)d_in[19];
    const float* lin_b = (const float*)d_in[20];
    float* out = (float*)d_out;

    // workspace layout (zero-region first)
    char* w = (char*)d_ws;
    size_t off = 0;
    auto alloc = [&](size_t bytes) -> void* {
        void* p = w + off;
        off = al256(off + bytes);
        return p;
    };
    int*   deg    = (int*)alloc((size_t)N * 4);
    int*   fill   = (int*)alloc((size_t)N * 4);
    int*   gcount = (int*)alloc((size_t)NGRAPH * 4);
    float* pooled = (float*)alloc((size_t)NGRAPH * HD * 4);
    size_t zbytes = off;
    int*   ptr    = (int*)alloc((size_t)(N + 1) * 4);
    int*   bsum   = (int*)alloc((size_t)1024 * 4);
    int*   csr    = (int*)alloc((size_t)E * 4);
    unsigned short* hA   = (unsigned short*)alloc((size_t)N * HD * 2);
    unsigned short* hB   = (unsigned short*)alloc((size_t)N * HD * 2);
    unsigned short* feat = (unsigned short*)alloc((size_t)N * HD * 2);
    unsigned short* Wt   = (unsigned short*)alloc((size_t)3 * HD * HD * 2);
    float* asA = (float*)alloc((size_t)N * 2 * 4);
    float* adA = (float*)alloc((size_t)N * 2 * 4);
    float* asB = (float*)alloc((size_t)N * 2 * 4);
    float* adB = (float*)alloc((size_t)N * 2 * 4);
    (void)ws_size; (void)n_in; (void)out_size;

    hipMemsetAsync(d_ws, 0, zbytes, stream);

    // weight prep + CSR by dst (reused by all 4 layers)
    k_prepw<<<(3 * HD * HD + 255) / 256, 256, 0, stream>>>(Wl[1], Wl[2], Wl[3], Wt);
    k_deg<<<(E + 255) / 256, 256, 0, stream>>>(edst, deg, E);
    const int SB = (N + 2047) / 2048;
    k_scan_local<<<SB, 256, 0, stream>>>(deg, ptr, bsum, N);
    k_scan_bsum<<<1, 64, 0, stream>>>(bsum, SB);
    k_scan_add<<<SB, 256, 0, stream>>>(ptr, bsum, N);
    k_scatter<<<(E + 255) / 256, 256, 0, stream>>>(esrc, edst, ptr, fill, csr, E);

    const int fblk = (N + 15) / 16;           // 16 nodes/block

    // layer 1 gemm + alpha -> hA, asA/adA
    k_gemm1_alpha<<<(N + 3) / 4, 256, 0, stream>>>(
        x, Wl[0], asr[0], ads[0], hA, asA, adA, N);

    const unsigned short* hc = hA; unsigned short* hn = hB;
    const float* cas = asA; const float* cad = adA;
    float* nas = asB;       float* nad = adB;
    for (int i = 0; i < 4; ++i) {
        if (i < 3) {
            k_agg_gemm<<<fblk, 256, 0, stream>>>(
                hc, cas, cad, ptr, csr, bs[i],
                Wt + (size_t)i * HD * HD, asr[i + 1], ads[i + 1],
                hn, nas, nad, N);
            // swap
            const unsigned short* th = hc; hc = hn; hn = (unsigned short*)th;
            const float* ts = cas; cas = nas; nas = (float*)ts;
            const float* td = cad; cad = nad; nad = (float*)td;
        } else {
            k_agg_final<<<fblk, 256, 0, stream>>>(
                hc, cas, cad, ptr, csr, bs[i], feat, N);
        }
    }

    k_pool<<<(N + 127) / 128, 128, 0, stream>>>(feat, batch, pooled, gcount, N);
    k_final<<<1, 320, 0, stream>>>(pooled, gcount, lin_w, lin_b, out);
}

// Round 10
// 337.191 us; speedup vs baseline: 1.7980x; 1.0022x over previous
//
#include <hip/hip_runtime.h>
#include <math.h>

// Problem constants (from reference)
#define NHEAD 2
#define NDIM  64
#define HD    128   // NHEAD*NDIM
#define NGRAPH 64
#define NCLS  5
#define NEG_SLOPE 0.2f
#define LDA 136     // padded LDS row stride (elements)
#define NRANGE 8    // src-node ranges (~1.6MB of h each) for gather L2 locality

typedef __attribute__((ext_vector_type(8))) short bf16x8;
typedef __attribute__((ext_vector_type(4))) float f32x4;

static __device__ __forceinline__ unsigned short f2bf(float f) {
    unsigned int u = __float_as_uint(f);
    u = (u + 0x7fff + ((u >> 16) & 1)) >> 16;   // round-to-nearest-even
    return (unsigned short)u;
}
static __device__ __forceinline__ float bf2f(unsigned short b) {
    return __uint_as_float((unsigned int)b << 16);
}

// ---------------- CSR build (segmented by (dst, src-range)) ----------------

__global__ void k_deg(const int* __restrict__ src, const int* __restrict__ dst,
                      int* __restrict__ deg, int E, int Rsz) {
    int i = blockIdx.x * blockDim.x + threadIdx.x;
    if (i < E) {
        int r = src[i] / Rsz;
        atomicAdd(&deg[(size_t)dst[i] * NRANGE + r], 1);
    }
}

__global__ __launch_bounds__(256) void k_scan_local(const int* __restrict__ deg,
                                                    int* __restrict__ ptr,
                                                    int* __restrict__ bsum, int n) {
    __shared__ int wsum[4];
    const int tid = threadIdx.x, lane = tid & 63, wid = tid >> 6;
    const int base = blockIdx.x * 2048 + tid * 8;
    int v[8];
    #pragma unroll
    for (int k = 0; k < 8; ++k) {
        int i = base + k;
        v[k] = (i < n) ? deg[i] : 0;
    }
    #pragma unroll
    for (int k = 1; k < 8; ++k) v[k] += v[k - 1];
    int x = v[7];
    #pragma unroll
    for (int off = 1; off < 64; off <<= 1) {
        int t = __shfl_up(x, off, 64);
        if (lane >= off) x += t;
    }
    if (lane == 63) wsum[wid] = x;
    __syncthreads();
    int woff = 0;
    #pragma unroll
    for (int k = 0; k < 4; ++k) woff += (k < wid) ? wsum[k] : 0;
    int texcl = woff + x - v[7];
    #pragma unroll
    for (int k = 0; k < 8; ++k) {
        int i = base + k;
        if (i < n) ptr[i + 1] = texcl + v[k];
    }
    if (tid == 255) bsum[blockIdx.x] = woff + x;
    if (blockIdx.x == 0 && tid == 0) ptr[0] = 0;
}

__global__ void k_scan_bsum(int* __restrict__ bsum, int B) {
    int lane = threadIdx.x;
    int carry = 0;
    for (int base = 0; base < B; base += 64) {
        int i = base + lane;
        int v = (i < B) ? bsum[i] : 0;
        int x = v;
        #pragma unroll
        for (int off = 1; off < 64; off <<= 1) {
            int t = __shfl_up(x, off, 64);
            if (lane >= off) x += t;
        }
        if (i < B) bsum[i] = carry + x - v;
        carry += __shfl(x, 63, 64);
    }
}

__global__ __launch_bounds__(256) void k_scan_add(int* __restrict__ ptr,
                                                  const int* __restrict__ bsum, int n) {
    int off = bsum[blockIdx.x];
    if (off == 0) return;
    const int base = blockIdx.x * 2048 + threadIdx.x * 8;
    #pragma unroll
    for (int k = 0; k < 8; ++k) {
        int i = base + k;
        if (i < n) ptr[i + 1] += off;
    }
}

__global__ void k_scatter(const int* __restrict__ src, const int* __restrict__ dst,
                          const int* __restrict__ ptr, int* __restrict__ fill,
                          int* __restrict__ csr, int E, int Rsz) {
    int i = blockIdx.x * blockDim.x + threadIdx.x;
    if (i < E) {
        int s = src[i];
        int seg = dst[i] * NRANGE + s / Rsz;
        int pos = atomicAdd(&fill[seg], 1);
        csr[ptr[seg] + pos] = s;
    }
}

// ---------------- weight prep: fp32 W[k][n] -> bf16 Wt[n][k] for layers 2-4 ------

__global__ void k_prepw(const float* __restrict__ W2, const float* __restrict__ W3,
                        const float* __restrict__ W4, unsigned short* __restrict__ Wt) {
    int idx = blockIdx.x * blockDim.x + threadIdx.x;
    if (idx >= 3 * HD * HD) return;
    int l = idx / (HD * HD), rem = idx % (HD * HD);
    int n = rem >> 7, k = rem & 127;
    const float* W = (l == 0) ? W2 : (l == 1) ? W3 : W4;
    Wt[idx] = f2bf(W[k * HD + n]);
}

// ---------------- layer 1: x[N,4] @ W[4,128] + fused alpha dots ----------------
__global__ void k_gemm1_alpha(const float* __restrict__ x, const float* __restrict__ W,
                              const float* __restrict__ asrc, const float* __restrict__ adst,
                              unsigned short* __restrict__ out, float* __restrict__ oas,
                              float* __restrict__ oad, int N) {
    int n = (blockIdx.x * blockDim.x + threadIdx.x) >> 6;
    int lane = threadIdx.x & 63;
    if (n >= N) return;
    float4 xv = *(const float4*)&x[n * 4];
    int c0 = lane * 2;
    float2 w0 = *(const float2*)&W[c0];
    float2 w1 = *(const float2*)&W[128 + c0];
    float2 w2 = *(const float2*)&W[256 + c0];
    float2 w3 = *(const float2*)&W[384 + c0];
    float v0 = xv.x * w0.x + xv.y * w1.x + xv.z * w2.x + xv.w * w3.x;
    float v1 = xv.x * w0.y + xv.y * w1.y + xv.z * w2.y + xv.w * w3.y;
    unsigned short b0 = f2bf(v0), b1 = f2bf(v1);
    unsigned int packed = (unsigned int)b0 | ((unsigned int)b1 << 16);
    *(unsigned int*)&out[(size_t)n * HD + c0] = packed;
    float vx = bf2f(b0), vy = bf2f(b1);
    float2 av = *(const float2*)&asrc[c0];
    float2 dv = *(const float2*)&adst[c0];
    float s = vx * av.x + vy * av.y;
    float t = vx * dv.x + vy * dv.y;
    #pragma unroll
    for (int off = 16; off > 0; off >>= 1) {
        s += __shfl_xor(s, off);
        t += __shfl_xor(t, off);
    }
    if ((lane & 31) == 0) {
        int head = lane >> 5;
        oas[n * 2 + head] = s;
        oad[n * 2 + head] = t;
    }
}

// ---------------- agg body: UNNORMALIZED gather+FMA -------------------------
// Quarter-wave (16 lanes) per node; lane covers dims sub*8..sub*8+8 (head=sub>>3).
// Node n's full edge list spans segments [8n, 8n+8) -> beg=ptr[8n], end=ptr[8n+8]
// (contiguous in csr, ordered by src-range: concurrent waves progress through
// src-ranges together -> instantaneous gather footprint ~2 ranges (~3.2MB),
// L2-resident per XCD).
static __device__ __forceinline__ void agg_acc(
    const unsigned short* __restrict__ h, const float* __restrict__ oas,
    const float* __restrict__ oad,
    const int* __restrict__ ptr, const int* __restrict__ csr,
    int n, int N, int sub, int hsel, float* acc, float& denom) {
    #pragma unroll
    for (int k = 0; k < 8; ++k) acc[k] = 0.f;
    denom = 0.f;
    if (n >= N) return;
    const int beg = ptr[n * NRANGE], end = ptr[n * NRANGE + NRANGE];
    const float adh = oad[n * 2 + hsel];

    auto weight = [&](float as) {
        float e = as + adh;
        e = (e >= 0.f) ? e : NEG_SLOPE * e;
        e = fminf(e, 80.f);
        return __expf(e);
    };
    auto accum = [&](uint4 hv, float a) {
        denom += a;
        #pragma unroll
        for (int k = 0; k < 4; ++k) {
            unsigned int u = (&hv.x)[k];
            acc[2 * k]     += a * __uint_as_float(u << 16);
            acc[2 * k + 1] += a * __uint_as_float(u & 0xffff0000u);
        }
    };

    int j = beg;
    for (; j + 4 <= end; j += 4) {
        int s0 = csr[j], s1 = csr[j + 1], s2 = csr[j + 2], s3 = csr[j + 3];
        uint4 h0 = *(const uint4*)&h[(size_t)s0 * HD + sub * 8];
        uint4 h1 = *(const uint4*)&h[(size_t)s1 * HD + sub * 8];
        uint4 h2 = *(const uint4*)&h[(size_t)s2 * HD + sub * 8];
        uint4 h3 = *(const uint4*)&h[(size_t)s3 * HD + sub * 8];
        float x0 = oas[s0 * 2 + hsel], x1 = oas[s1 * 2 + hsel];
        float x2 = oas[s2 * 2 + hsel], x3 = oas[s3 * 2 + hsel];
        accum(h0, weight(x0));
        accum(h1, weight(x1));
        accum(h2, weight(x2));
        accum(h3, weight(x3));
    }
    for (; j < end; ++j) {
        int s = csr[j];
        uint4 hv = *(const uint4*)&h[(size_t)s * HD + sub * 8];
        float xs = oas[s * 2 + hsel];
        accum(hv, weight(xs));
    }
}

static __device__ __forceinline__ uint4 norm_bias_relu_pack(
    const float* acc, float denom, const float* __restrict__ bias, int sub) {
    float inv = 1.f / (denom + 1e-16f);
    float4 ba = *(const float4*)&bias[sub * 8];
    float4 bb = *(const float4*)&bias[sub * 8 + 4];
    float o[8];
    o[0] = fmaxf(acc[0] * inv + ba.x, 0.f);
    o[1] = fmaxf(acc[1] * inv + ba.y, 0.f);
    o[2] = fmaxf(acc[2] * inv + ba.z, 0.f);
    o[3] = fmaxf(acc[3] * inv + ba.w, 0.f);
    o[4] = fmaxf(acc[4] * inv + bb.x, 0.f);
    o[5] = fmaxf(acc[5] * inv + bb.y, 0.f);
    o[6] = fmaxf(acc[6] * inv + bb.z, 0.f);
    o[7] = fmaxf(acc[7] * inv + bb.w, 0.f);
    uint4 pk;
    pk.x = (unsigned int)f2bf(o[0]) | ((unsigned int)f2bf(o[1]) << 16);
    pk.y = (unsigned int)f2bf(o[2]) | ((unsigned int)f2bf(o[3]) << 16);
    pk.z = (unsigned int)f2bf(o[4]) | ((unsigned int)f2bf(o[5]) << 16);
    pk.w = (unsigned int)f2bf(o[6]) | ((unsigned int)f2bf(o[7]) << 16);
    return pk;
}

// ---------------- fused layer: agg(l) -> LDS -> gemm(l+1) + alpha ----------
// 16 nodes/block (quarter-wave per node). GEMM col-split across waves; output
// staged in LDS and written as full coalesced 256B rows.
__global__ __launch_bounds__(256, 8) void k_agg_gemm(
    const unsigned short* __restrict__ hin,
    const float* __restrict__ oas_in, const float* __restrict__ oad_in,
    const int* __restrict__ ptr, const int* __restrict__ csr,
    const float* __restrict__ bias,             // agg bias (layer l)
    const unsigned short* __restrict__ Wt,      // layer l+1 weight, [n][k] bf16
    const float* __restrict__ asrc, const float* __restrict__ adst,  // layer l+1
    unsigned short* __restrict__ hout,
    float* __restrict__ oas_out, float* __restrict__ oad_out, int N) {
    __shared__ unsigned short As[16 * LDA];
    __shared__ unsigned short Ot[16][HD];
    __shared__ float psL[4][16], pdL[4][16];
    const int tid = threadIdx.x;
    const int lane = tid & 63, w = tid >> 6;
    const int grp = lane >> 4, sub = lane & 15;
    const int hsel = sub >> 3;
    const int nbase = blockIdx.x * 16;

    // ---- agg phase ----
    const int row = w * 4 + grp;
    float acc8[8], denom;
    agg_acc(hin, oas_in, oad_in, ptr, csr, nbase + row, N, sub, hsel, acc8, denom);
    uint4 pk = norm_bias_relu_pack(acc8, denom, bias, sub);
    *(uint4*)&As[(size_t)row * LDA + sub * 8] = pk;
    __syncthreads();

    // ---- gemm phase: wave w owns cols c in {2w, 2w+1} ----
    float av2[2], dv2[2];
    #pragma unroll
    for (int i = 0; i < 2; ++i) {
        int c = w * 2 + i;
        av2[i] = asrc[c * 16 + sub];
        dv2[i] = adst[c * 16 + sub];
    }
    f32x4 acc[2];
    acc[0] = (f32x4)(0.f);
    acc[1] = (f32x4)(0.f);
    #pragma unroll
    for (int ks = 0; ks < 4; ++ks) {
        bf16x8 a0 = *(const bf16x8*)&As[(size_t)sub * LDA + ks * 32 + grp * 8];
        #pragma unroll
        for (int i = 0; i < 2; ++i) {
            int c = w * 2 + i;
            bf16x8 b = *(const bf16x8*)&Wt[(size_t)(c * 16 + sub) * HD + ks * 32 + grp * 8];
            acc[i] = __builtin_amdgcn_mfma_f32_16x16x32_bf16(a0, b, acc[i], 0, 0, 0);
        }
    }

    // stage output tile (D: row = grp*4 + r, col = c*16 + sub)
    #pragma unroll
    for (int i = 0; i < 2; ++i) {
        int col = (w * 2 + i) * 16 + sub;
        #pragma unroll
        for (int r = 0; r < 4; ++r)
            Ot[grp * 4 + r][col] = f2bf(acc[i][r]);
    }
    // alpha partials (each wave covers half of one head's 64 cols)
    #pragma unroll
    for (int r = 0; r < 4; ++r) {
        float ps = acc[0][r] * av2[0] + acc[1][r] * av2[1];
        float pd = acc[0][r] * dv2[0] + acc[1][r] * dv2[1];
        #pragma unroll
        for (int off = 1; off < 16; off <<= 1) {
            ps += __shfl_xor(ps, off);
            pd += __shfl_xor(pd, off);
        }
        if (sub == 0) {
            psL[w][grp * 4 + r] = ps;
            pdL[w][grp * 4 + r] = pd;
        }
    }
    __syncthreads();

    // coalesced full-row writes: thread t -> row t>>4, 16B chunk t&15
    {
        int r2 = tid >> 4, c16 = tid & 15;
        int gn = nbase + r2;
        if (gn < N) {
            uint4 v = *(const uint4*)&Ot[r2][c16 * 8];
            *(uint4*)&hout[(size_t)gn * HD + c16 * 8] = v;
        }
    }
    if (tid < 32) {
        int r2 = tid & 15, head = tid >> 4;
        int n2 = nbase + r2;
        if (n2 < N) {
            float s = psL[2 * head][r2] + psL[2 * head + 1][r2];
            float d = pdL[2 * head][r2] + pdL[2 * head + 1][r2];
            oas_out[n2 * 2 + head] = s;
            oad_out[n2 * 2 + head] = d;
        }
    }
}

// ---------------- final agg (layer 4): writes feat to global ----------------
__global__ __launch_bounds__(256) void k_agg_final(
    const unsigned short* __restrict__ hin,
    const float* __restrict__ oas_in, const float* __restrict__ oad_in,
    const int* __restrict__ ptr, const int* __restrict__ csr,
    const float* __restrict__ bias,
    unsigned short* __restrict__ out, int N) {
    const int tid = threadIdx.x;
    const int lane = tid & 63;
    const int grp = lane >> 4, sub = lane & 15;
    const int hsel = sub >> 3;
    const int n = ((blockIdx.x * blockDim.x + tid) >> 6) * 4 + grp;
    float acc8[8], denom;
    agg_acc(hin, oas_in, oad_in, ptr, csr, n, N, sub, hsel, acc8, denom);
    if (n < N) {
        uint4 pk = norm_bias_relu_pack(acc8, denom, bias, sub);
        *(uint4*)&out[(size_t)n * HD + sub * 8] = pk;
    }
}

// ---------------- pooling (fused graph-size count) ----------------
__global__ void k_pool(const unsigned short* __restrict__ feat, const int* __restrict__ batch,
                       float* __restrict__ pooled, int* __restrict__ gcount, int N) {
    int col = threadIdx.x;
    int n0 = blockIdx.x * 128;
    int n1 = min(n0 + 128, N);
    float acc = 0.f;
    int curg = -1, runlen = 0;
    for (int n = n0; n < n1; ++n) {
        int g = batch[n];
        if (g != curg) {
            if (curg >= 0) {
                atomicAdd(&pooled[curg * HD + col], acc);
                if (col == 0) atomicAdd(&gcount[curg], runlen);
            }
            acc = 0.f; runlen = 0;
            curg = g;
        }
        acc += bf2f(feat[(size_t)n * HD + col]);
        runlen++;
    }
    if (curg >= 0) {
        atomicAdd(&pooled[curg * HD + col], acc);
        if (col == 0) atomicAdd(&gcount[curg], runlen);
    }
}

__global__ void k_final(const float* __restrict__ pooled, const int* __restrict__ gcount,
                        const float* __restrict__ lw, const float* __restrict__ lb,
                        float* __restrict__ out) {
    int tid = threadIdx.x;
    if (tid >= NGRAPH * NCLS) return;
    int g = tid / NCLS, c = tid % NCLS;
    float cnt = fmaxf((float)gcount[g], 1.f);
    const float* p = pooled + g * HD;
    float sum = 0.f;
    for (int k = 0; k < HD; ++k)
        sum += p[k] * lw[k * NCLS + c];
    float z = lb[c] + sum / cnt;
    out[tid] = 1.f / (1.f + __expf(-z));
}

// ---------------- launch ----------------

static inline size_t al256(size_t x) { return (x + 255) & ~(size_t)255; }

extern "C" void kernel_launch(void* const* d_in, const int* in_sizes, int n_in,
                              void* d_out, int out_size, void* d_ws, size_t ws_size,
                              hipStream_t stream) {
    const int N = in_sizes[0] / 4;   // x is [N,4]
    const int E = in_sizes[1] / 2;   // edge_index is [2,E]
    const int Rsz = (N + NRANGE - 1) / NRANGE;
    const int NSEG = N * NRANGE;

    const float* x     = (const float*)d_in[0];
    const int*   esrc  = (const int*)d_in[1];
    const int*   edst  = esrc + E;
    const int*   batch = (const int*)d_in[2];
    const float* Wl[4]  = {(const float*)d_in[3],  (const float*)d_in[7],
                           (const float*)d_in[11], (const float*)d_in[15]};
    const float* asr[4] = {(const float*)d_in[4],  (const float*)d_in[8],
                           (const float*)d_in[12], (const float*)d_in[16]};
    const float* ads[4] = {(const float*)d_in[5],  (const float*)d_in[9],
                           (const float*)d_in[13], (const float*)d_in[17]};
    const float* bs[4]  = {(const float*)d_in[6],  (const float*)d_in[10],
                           (const float*)d_in[14], (const float*)d_in[18]};
    const float* lin_w = (const float*)d_in[19];
    const float* lin_b = (const float*)d_in[20];
    float* out = (float*)d_out;

    // workspace layout (zero-region first)
    char* w = (char*)d_ws;
    size_t off = 0;
    auto alloc = [&](size_t bytes) -> void* {
        void* p = w + off;
        off = al256(off + bytes);
        return p;
    };
    int*   deg    = (int*)alloc((size_t)NSEG * 4);
    int*   fill   = (int*)alloc((size_t)NSEG * 4);
    int*   gcount = (int*)alloc((size_t)NGRAPH * 4);
    float* pooled = (float*)alloc((size_t)NGRAPH * HD * 4);
    size_t zbytes = off;
    int*   ptr    = (int*)alloc((size_t)(NSEG + 1) * 4);
    int*   bsum   = (int*)alloc((size_t)1024 * 4);
    int*   csr    = (int*)alloc((size_t)E * 4);
    unsigned short* hA   = (unsigned short*)alloc((size_t)N * HD * 2);
    unsigned short* hB   = (unsigned short*)alloc((size_t)N * HD * 2);
    unsigned short* feat = (unsigned short*)alloc((size_t)N * HD * 2);
    unsigned short* Wt   = (unsigned short*)alloc((size_t)3 * HD * HD * 2);
    float* asA = (float*)alloc((size_t)N * 2 * 4);
    float* adA = (float*)alloc((size_t)N * 2 * 4);
    float* asB = (float*)alloc((size_t)N * 2 * 4);
    float* adB = (float*)alloc((size_t)N * 2 * 4);
    (void)ws_size; (void)n_in; (void)out_size;

    hipMemsetAsync(d_ws, 0, zbytes, stream);

    // weight prep + segmented CSR (dst-major, src-range-minor; reused all layers)
    k_prepw<<<(3 * HD * HD + 255) / 256, 256, 0, stream>>>(Wl[1], Wl[2], Wl[3], Wt);
    k_deg<<<(E + 255) / 256, 256, 0, stream>>>(esrc, edst, deg, E, Rsz);
    const int SB = (NSEG + 2047) / 2048;
    k_scan_local<<<SB, 256, 0, stream>>>(deg, ptr, bsum, NSEG);
    k_scan_bsum<<<1, 64, 0, stream>>>(bsum, SB);
    k_scan_add<<<SB, 256, 0, stream>>>(ptr, bsum, NSEG);
    k_scatter<<<(E + 255) / 256, 256, 0, stream>>>(esrc, edst, ptr, fill, csr, E, Rsz);

    const int fblk = (N + 15) / 16;           // 16 nodes/block

    // layer 1 gemm + alpha -> hA, asA/adA
    k_gemm1_alpha<<<(N + 3) / 4, 256, 0, stream>>>(
        x, Wl[0], asr[0], ads[0], hA, asA, adA, N);

    const unsigned short* hc = hA; unsigned short* hn = hB;
    const float* cas = asA; const float* cad = adA;
    float* nas = asB;       float* nad = adB;
    for (int i = 0; i < 4; ++i) {
        if (i < 3) {
            k_agg_gemm<<<fblk, 256, 0, stream>>>(
                hc, cas, cad, ptr, csr, bs[i],
                Wt + (size_t)i * HD * HD, asr[i + 1], ads[i + 1],
                hn, nas, nad, N);
            // swap
            const unsigned short* th = hc; hc = hn; hn = (unsigned short*)th;
            const float* ts = cas; cas = nas; nas = (float*)ts;
            const float* td = cad; cad = nad; nad = (float*)td;
        } else {
            k_agg_final<<<fblk, 256, 0, stream>>>(
                hc, cas, cad, ptr, csr, bs[i], feat, N);
        }
    }

    k_pool<<<(N + 127) / 128, 128, 0, stream>>>(feat, batch, pooled, gcount, N);
    k_final<<<1, 320, 0, stream>>>(pooled, gcount, lin_w, lin_b, out);
}